// Round 6
// baseline (142.243 us; speedup 1.0000x reference)
//
#include <hip/hip_runtime.h>
#include <math.h>

#define HH 2048
#define WW 2048
#define HWP (HH*WW)          // plane stride (elements)
#define NBLK 64              // spatial 8x8 blocks per workgroup (512-col strip)
#define SLOTH 72             // halves per (c,blk) slot; 144B stride -> 0 conflicts (measured R4/R5)

typedef _Float16  h8 __attribute__((ext_vector_type(8)));   // 16B LDS vector

// ---- f64 truth for 0.5*cos(pi*m/16); f32 casts == np.float32(A) exactly ----
#define C1d 0.49039264020161522
#define C2d 0.46193976625564337
#define C3d 0.41573480615127262
#define C4d 0.35355339059327379
#define C5d 0.27778511650980111
#define C6d 0.19134171618254489
#define C7d 0.097545161008064134
#define F(x) ((float)(x))

static constexpr float AFc[8][8] = {
 { F(C4d), F(C4d), F(C4d), F(C4d), F(C4d), F(C4d), F(C4d), F(C4d)},
 { F(C1d), F(C3d), F(C5d), F(C7d),-F(C7d),-F(C5d),-F(C3d),-F(C1d)},
 { F(C2d), F(C6d),-F(C6d),-F(C2d),-F(C2d),-F(C6d), F(C6d), F(C2d)},
 { F(C3d),-F(C7d),-F(C1d),-F(C5d), F(C5d), F(C1d), F(C7d),-F(C3d)},
 { F(C4d),-F(C4d),-F(C4d), F(C4d), F(C4d),-F(C4d),-F(C4d), F(C4d)},
 { F(C5d),-F(C1d), F(C7d), F(C3d),-F(C3d),-F(C7d), F(C1d),-F(C5d)},
 { F(C6d),-F(C2d), F(C2d),-F(C6d),-F(C6d), F(C2d),-F(C2d), F(C6d)},
 { F(C7d),-F(C5d), F(C3d),-F(C1d), F(C1d),-F(C3d), F(C5d),-F(C7d)}
};

__device__ __constant__ float g_AF[64] = {
  F(C4d), F(C4d), F(C4d), F(C4d), F(C4d), F(C4d), F(C4d), F(C4d),
  F(C1d), F(C3d), F(C5d), F(C7d),-F(C7d),-F(C5d),-F(C3d),-F(C1d),
  F(C2d), F(C6d),-F(C6d),-F(C2d),-F(C2d),-F(C6d), F(C6d), F(C2d),
  F(C3d),-F(C7d),-F(C1d),-F(C5d), F(C5d), F(C1d), F(C7d),-F(C3d),
  F(C4d),-F(C4d),-F(C4d), F(C4d), F(C4d),-F(C4d),-F(C4d), F(C4d),
  F(C5d),-F(C1d), F(C7d), F(C3d),-F(C3d),-F(C7d), F(C1d),-F(C5d),
  F(C6d),-F(C2d), F(C2d),-F(C6d),-F(C6d), F(C2d),-F(C2d), F(C6d),
  F(C7d),-F(C5d), F(C3d),-F(C1d), F(C1d),-F(C3d), F(C5d),-F(C7d)
};

__device__ __constant__ float g_Q[128] = {
 16,11,10,16,24,40,51,61,  12,12,14,19,26,58,60,55,
 14,13,16,24,40,57,69,56,  14,17,22,29,51,87,80,62,
 18,22,37,56,68,109,103,77, 24,35,55,64,81,104,113,92,
 49,64,78,87,103,121,120,101, 72,92,95,98,112,100,103,99,
 17,18,24,47,99,99,99,99,  18,21,26,66,99,99,99,99,
 24,26,56,99,99,99,99,99,  47,66,99,99,99,99,99,99,
 99,99,99,99,99,99,99,99,  99,99,99,99,99,99,99,99,
 99,99,99,99,99,99,99,99,  99,99,99,99,99,99,99,99};

// ---- color constants: np's _w is float32; inverse from the f32-rounded w ----
static constexpr double W00=(double)0.299f,     W01=(double)0.587f,     W02=(double)0.114f;
static constexpr double W10=(double)-0.168736f, W11=(double)-0.331264f, W12=(double)0.5f;
static constexpr double W20=(double)0.5f,       W21=(double)-0.418688f, W22=(double)-0.081312f;
static constexpr double DETW = W00*(W11*W22 - W12*W21) - W01*(W10*W22 - W12*W20)
                             + W02*(W10*W21 - W11*W20);
static constexpr double I00=(W11*W22-W12*W21)/DETW, I01=(W02*W21-W01*W22)/DETW, I02=(W01*W12-W02*W11)/DETW;
static constexpr double I10=(W12*W20-W10*W22)/DETW, I11=(W00*W22-W02*W20)/DETW, I12=(W02*W10-W00*W12)/DETW;
static constexpr double I20=(W10*W21-W11*W20)/DETW, I21=(W01*W20-W00*W21)/DETW, I22=(W00*W11-W01*W10)/DETW;
static constexpr float  m0f = 125.3f/255.0f, m1f = 123.0f/255.0f, m2f = 113.9f/255.0f;
static constexpr float  s0f = 63.0f/255.0f,  s1f = 62.1f/255.0f,  s2f = 66.7f/255.0f;
static constexpr double M0d = 255.0*(double)m0f, M1d = 255.0*(double)m1f, M2d = 255.0*(double)m2f;
static constexpr double iS0d = 1.0/(255.0*(double)s0f), iS1d = 1.0/(255.0*(double)s1f), iS2d = 1.0/(255.0*(double)s2f);

__global__ void __launch_bounds__(192, 4)
jpeg_kernel(const float* __restrict__ in, float* __restrict__ out) {
#pragma clang fp contract(off)   // pre-round path must not fuse mul+add
  __shared__ _Float16 recs[3 * NBLK * SLOTH];   // 27648 B
  __shared__ float Alds[64];
  __shared__ float Qlds[128];

  const int tid  = threadIdx.x;
  const int gid  = blockIdx.x;        // 0..1023
  const int brow = gid >> 2;          // block-row 0..255
  const int strip = gid & 3;
  const int rowbase = brow * 8;
  const int colbase = strip * 512;
  const int c   = tid >> 6;           // channel 0..2 (wave-uniform)
  const int blk = tid & 63;           // 8x8 block within strip

  if (tid < 64)        Alds[tid] = g_AF[tid];
  else if (tid < 192)  Qlds[tid - 64] = g_Q[tid - 64];
  __syncthreads();

  const float* pR = in;
  const float* pG = in + HWP;
  const float* pB = in + 2 * HWP;
  const size_t base = (size_t)rowbase * WW + colbase + blk * 8;

  // per-wave forward color row (f32, as np's _w)
  float wc0, wc1, wc2, bc;
  if (c == 0)      { wc0 = 0.299f;     wc1 = 0.587f;     wc2 = 0.114f;     bc = 0.0f;   }
  else if (c == 1) { wc0 = -0.168736f; wc1 = -0.331264f; wc2 = 0.5f;       bc = 128.0f; }
  else             { wc0 = 0.5f;       wc1 = -0.418688f; wc2 = -0.081312f; bc = 128.0f; }

  // ---- Fused pipelined loop: j-outer. Row j's RGB is consumed immediately;
  // row j+1's loads issue before the 1088-op DCT body (latency fully hidden).
  // For each fixed (i,l), adds happen in (j,k) lex order with identical
  // fl(fl(aij*Xjk)*Alk) terms -> BIT-IDENTICAL to the passing R3/R4 kernel.
  float accs[64];                       // [i*8+l], lives in VGPRs
  #pragma unroll
  for (int t = 0; t < 64; ++t) accs[t] = 0.0f;

  float4 Ra = *(const float4*)(pR + base),         Rb = *(const float4*)(pR + base + 4);
  float4 Ga = *(const float4*)(pG + base),         Gb = *(const float4*)(pG + base + 4);
  float4 Ba = *(const float4*)(pB + base),         Bb = *(const float4*)(pB + base + 4);

  for (int j = 0; j < 8; ++j) {         // runtime loop (icache: body ~1.1K instr)
    const float fr[8] = {Ra.x,Ra.y,Ra.z,Ra.w,Rb.x,Rb.y,Rb.z,Rb.w};
    const float fg[8] = {Ga.x,Ga.y,Ga.z,Ga.w,Gb.x,Gb.y,Gb.z,Gb.w};
    const float fb[8] = {Ba.x,Ba.y,Ba.z,Ba.w,Bb.x,Bb.y,Bb.z,Bb.w};
    if (j < 7) {                        // prefetch row j+1
      const size_t nb = base + (size_t)(j + 1) * WW;
      Ra = *(const float4*)(pR + nb); Rb = *(const float4*)(pR + nb + 4);
      Ga = *(const float4*)(pG + nb); Gb = *(const float4*)(pG + nb + 4);
      Ba = *(const float4*)(pB + nb); Bb = *(const float4*)(pB + nb + 4);
    }
    float Xj[8];
    #pragma unroll
    for (int p = 0; p < 8; ++p) {       // YUV row j (bit-identical order)
      float acc = fmaf(wc2, fb[p], fmaf(wc1, fg[p], wc0 * fr[p]));
      Xj[p] = acc + bc;
    }
    #pragma unroll
    for (int i = 0; i < 8; ++i) {
      const float aij = Alds[i*8 + j];  // lane-uniform LDS broadcast
      float P[8];
      #pragma unroll
      for (int k = 0; k < 8; ++k) P[k] = aij * Xj[k];       // fl(aij*Xjk)
      #pragma unroll
      for (int l = 0; l < 8; ++l) {
        #pragma unroll
        for (int k = 0; k < 8; ++k)
          accs[i*8+l] = accs[i*8+l] + P[k] * AFc[l][k];     // seq add, k asc
      }
    }
  }

  // ---- Quant epilogue (bit-identical to R3/R4), in registers ----
  const int qoff = (c == 0) ? 0 : 64;
  #pragma unroll
  for (int i = 0; i < 8; ++i) {
    #pragma unroll
    for (int l = 0; l < 8; ++l) {
      const float q  = Qlds[qoff + i*8 + l];
      const float v  = accs[i*8+l] / q;   // IEEE f32 divide
      const float rr = rintf(v);          // half-to-even == np.round
      const float e  = v - rr;
      accs[i*8+l] = (rr + (e * e) * e) * q;   // U, in place
    }
  }

  // ---- IDCT fully in registers (post-round smooth; fma fine) ----
  #pragma unroll
  for (int i = 0; i < 8; ++i) {          // row pass: V[i][n] = sum_k U[i][k]*A[k][n]
    float t[8];
    #pragma unroll
    for (int n = 0; n < 8; ++n) {
      float a = accs[i*8+0] * AFc[0][n];
      #pragma unroll
      for (int k = 1; k < 8; ++k) a = fmaf(accs[i*8+k], AFc[k][n], a);
      t[n] = a;
    }
    #pragma unroll
    for (int n = 0; n < 8; ++n) accs[i*8+n] = t[n];   // V, in place
  }
  _Float16* slot = recs + (c * NBLK + blk) * SLOTH;
  #pragma unroll
  for (int m = 0; m < 8; ++m) {          // col pass: rec[m][n] = sum_j A[j][m]*V[j][n]
    h8 rh;
    #pragma unroll
    for (int n = 0; n < 8; ++n) {
      float a = AFc[0][m] * accs[0*8+n];
      #pragma unroll
      for (int j = 1; j < 8; ++j) a = fmaf(AFc[j][m], accs[j*8+n], a);
      rh[n] = (_Float16)a;               // single f16 staging (as R4)
    }
    *(h8*)(slot + m*8) = rh;             // conflict-free b128 (measured 0 in R4)
  }
  __syncthreads();                       // the one cross-channel barrier

  // ---- Phase D: YUV->RGB->normalize; 8 pixels/group, coalesced stores ----
  const float i00=F(I00), i01=F(I01), i02=F(I02);
  const float i10=F(I10), i11=F(I11), i12=F(I12);
  const float i20=F(I20), i21=F(I21), i22=F(I22);
  const float M0=F(M0d), M1=F(M1d), M2=F(M2d);
  const float iS0=F(iS0d), iS1=F(iS1d), iS2=F(iS2d);
  for (int g = tid; g < 512; g += 192) {
    const int b = g & 63;
    const int r = g >> 6;
    const h8 Yv = *(const h8*)(recs + (0*NBLK + b)*SLOTH + r*8);
    const h8 Uv = *(const h8*)(recs + (1*NBLK + b)*SLOTH + r*8);
    const h8 Vv = *(const h8*)(recs + (2*NBLK + b)*SLOTH + r*8);
    float o0[8], o1[8], o2[8];
    #pragma unroll
    for (int p = 0; p < 8; ++p) {
      const float yy = (float)Yv[p];
      const float uu = (float)Uv[p] - 128.0f;
      const float vv = (float)Vv[p] - 128.0f;
      o0[p] = (fmaf(i02, vv, fmaf(i01, uu, i00*yy)) - M0) * iS0;
      o1[p] = (fmaf(i12, vv, fmaf(i11, uu, i10*yy)) - M1) * iS1;
      o2[p] = (fmaf(i22, vv, fmaf(i21, uu, i20*yy)) - M2) * iS2;
    }
    const size_t off = (size_t)(rowbase + r) * WW + colbase + b * 8;
    *(float4*)(out + off)             = make_float4(o0[0],o0[1],o0[2],o0[3]);
    *(float4*)(out + off + 4)         = make_float4(o0[4],o0[5],o0[6],o0[7]);
    *(float4*)(out + HWP + off)       = make_float4(o1[0],o1[1],o1[2],o1[3]);
    *(float4*)(out + HWP + off + 4)   = make_float4(o1[4],o1[5],o1[6],o1[7]);
    *(float4*)(out + 2*HWP + off)     = make_float4(o2[0],o2[1],o2[2],o2[3]);
    *(float4*)(out + 2*HWP + off + 4) = make_float4(o2[4],o2[5],o2[6],o2[7]);
  }
}

extern "C" void kernel_launch(void* const* d_in, const int* in_sizes, int n_in,
                              void* d_out, int out_size, void* d_ws, size_t ws_size,
                              hipStream_t stream) {
  const float* in = (const float*)d_in[0];
  float* out = (float*)d_out;
  dim3 grid((HH/8) * (WW/512));   // 1024 workgroups = 4 per CU
  dim3 block(192);                // 3 waves: one per channel, 64 blocks each
  jpeg_kernel<<<grid, block, 0, stream>>>(in, out);
}